// Round 1
// 1263.090 us; speedup vs baseline: 1.4053x; 1.4053x over previous
//
#include <hip/hip_runtime.h>
#include <math.h>

#define BS 4
#define HH 480
#define WW 640
#define NPX (HH * WW)          // 307200
#define NC 16
#define CHN 20
#define MM 480
#define VRD 100
#define ZHD 80
#define MINZ 9
#define MAXZ 49
#define CAP 8192                // records per (b, y-bucket)

// d_out float offsets
#define OFF0 0                  // fp_map_pred (40000)
#define OFF1 40000              // map_pred (18432000)  [scratch: rotated mid]
#define OFF2 18472000           // current_poses (12)
#define OFF3 18472012           // current_poses (12)
#define OFF4 18472024           // translated (18432000)
#define OFFM 28840000           // maps scratch 4*18*100*100 = 720000 (inside OFF4, dead until translate)
#define OFFR 29560000           // records: 400*8192*2 floats = 6553600 (inside OFF4)
#define OFFC 36113600           // counters: 400*16 ints (inside OFF4)

__device__ __forceinline__ void pix2pos(int w, int h, float depth, float ca, float sa,
                                        float foc, float& px, float& py, float& pz) {
    float gx = (float)w;
    float gz = (float)(HH - 1 - h);
    float Xp = (gx - 319.5f) * depth / foc;
    float Zp = (gz - 239.5f) * depth / foc;
    float Yv = ca * depth - sa * Zp;
    float Zv = sa * depth + ca * Zp + 155.0f;
    float Xv = Xp + 250.0f;
    float xs = (Xv / 5.0f - 50.0f) / 100.0f * 2.0f;
    float ys = (Yv / 5.0f - 50.0f) / 100.0f * 2.0f;
    float zs = (Zv / 5.0f - 32.0f) / 80.0f * 2.0f;
    px = xs * 50.0f + 50.0f;
    py = ys * 50.0f + 50.0f;
    pz = zs * 40.0f + 40.0f;
}

__global__ __launch_bounds__(256) void bin_kernel(const float* __restrict__ obs,
                                                  const float* __restrict__ va,
                                                  int* __restrict__ cnt,
                                                  float2* __restrict__ rec,
                                                  float foc) {
    int idx = blockIdx.x * blockDim.x + threadIdx.x;
    if (idx >= BS * NPX) return;
    int b   = idx / NPX;
    int rem = idx % NPX;
    float depth = obs[((size_t)b * CHN + 3) * NPX + rem];
    int h = rem / WW, w = rem % WW;
    float a  = va[b] * 0.017453292519943295f;
    float ca = cosf(a), sa = sinf(a);
    float px, py, pz;
    pix2pos(w, h, depth, ca, sa, foc, px, py, pz);
    int f = (int)floorf(py);
    if (f < 0 || f > 99) return;
    int slot = atomicAdd(cnt + (b * VRD + f) * 16, 1);
    if (slot < CAP) {
        float2 r; r.x = __int_as_float(rem); r.y = depth;
        rec[(size_t)(b * VRD + f) * CAP + slot] = r;
    }
}

// one workgroup per (y-slice s, batch b): occupancy splat in LDS, fused z-reduction
__global__ __launch_bounds__(256) void slice_v0_kernel(const int* __restrict__ cnt,
                                                       const float2* __restrict__ rec,
                                                       const float* __restrict__ va,
                                                       float* __restrict__ maps,
                                                       float* __restrict__ out0,
                                                       float foc) {
    __shared__ float acc[VRD * ZHD];   // 32 KB
    int s = blockIdx.x;
    int b = blockIdx.y;
    int tid = threadIdx.x;
    for (int i = tid; i < VRD * ZHD; i += 256) acc[i] = 0.0f;
    __syncthreads();

    float a  = va[b] * 0.017453292519943295f;
    float ca = cosf(a), sa = sinf(a);
    int sm1 = (s > 0) ? s - 1 : 0;
    int n0 = (s > 0) ? min(cnt[(b * VRD + sm1) * 16], CAP) : 0;
    int n1 = min(cnt[(b * VRD + s) * 16], CAP);
    const float2* r0 = rec + (size_t)(b * VRD + sm1) * CAP;
    const float2* r1 = rec + (size_t)(b * VRD + s) * CAP;
    int N = n0 + n1;
    float fs = (float)s;

    for (int t = tid; t < N; t += 256) {
        float2 rv = (t < n0) ? r0[t] : r1[t - n0];
        int rem = __float_as_int(rv.x);
        float depth = rv.y;
        float px, py, pz;
        pix2pos(rem % WW, rem / WW, depth, ca, sa, foc, px, py, pz);
        float wy = 1.0f - fabsf(py - fs);
        if (s == 0 || wy <= 0.0f) continue;
        float fx = floorf(px), fz = floorf(pz);
        #pragma unroll
        for (int i = 0; i < 2; i++) {
            float cxp = fx + (float)i;
            if (!(cxp > 0.0f && cxp < 100.0f)) continue;
            float wxv = 1.0f - fabsf(px - cxp);
            int xi = (int)cxp;
            #pragma unroll
            for (int k = 0; k < 2; k++) {
                float czp = fz + (float)k;
                if (!(czp > 0.0f && czp < 80.0f)) continue;
                float wzv = 1.0f - fabsf(pz - czp);
                float wv = wy * wxv * wzv;
                if (wv != 0.0f) atomicAdd(&acc[xi * ZHD + (int)czp], wv);
            }
        }
    }
    __syncthreads();

    if (tid < VRD) {
        float s_all = 0.0f, s_agg = 0.0f;
        #pragma unroll 4
        for (int z = 0; z < ZHD; z++) {
            float r = rintf(acc[tid * ZHD + z]);
            s_all += r;
            if (z >= MINZ && z < MAXZ) s_agg += r;
        }
        float fm = fminf(fmaxf(s_agg, 0.0f), 1.0f);
        float fe = fminf(fmaxf(s_all, 0.0f), 1.0f);
        maps[((size_t)(b * 18 + 0) * VRD + s) * VRD + tid] = fm;
        maps[((size_t)(b * 18 + 1) * VRD + s) * VRD + tid] = fe;
        out0[((size_t)b * VRD + s) * VRD + tid] = fm;
    }
}

// channel-split: one workgroup per (y-slice s, batch b, channel-group cg of 2).
// Full cat z-range [9,49) fits in 32 KB LDS -> no chunk loop; each WG gathers
// only 2 semantic planes (2.4 MB, L2-resident). XCD-bijective swizzle keeps
// the ~resident WGs of one XCD on ~1-2 (b,cg) groups for L2 locality.
__global__ __launch_bounds__(256, 5) void slice_vc_kernel(const float* __restrict__ obs,
                                                          const int* __restrict__ cnt,
                                                          const float2* __restrict__ rec,
                                                          const float* __restrict__ va,
                                                          float* __restrict__ maps,
                                                          float foc) {
    __shared__ float acc[40 * VRD * 2];   // [z][x][c], 32 KB
    int bid  = blockIdx.x;                 // 0..3199
    int wgid = (bid & 7) * 400 + (bid >> 3);   // bijective XCD swizzle (3200 % 8 == 0)
    int s  = wgid % VRD;
    int p  = wgid / VRD;                   // 0..31: (cg,b) pair
    int b  = p & 3;
    int cg = p >> 2;                       // 0..7, owns channels {2cg, 2cg+1}
    int tid = threadIdx.x;
    for (int i = tid; i < 40 * VRD * 2; i += 256) acc[i] = 0.0f;
    __syncthreads();

    float a  = va[b] * 0.017453292519943295f;
    float ca = cosf(a), sa = sinf(a);
    int sm1 = (s > 0) ? s - 1 : 0;
    int n0 = (s > 0) ? min(cnt[(b * VRD + sm1) * 16], CAP) : 0;
    int n1 = min(cnt[(b * VRD + s) * 16], CAP);
    const float2* r0 = rec + (size_t)(b * VRD + sm1) * CAP;
    const float2* r1 = rec + (size_t)(b * VRD + s) * CAP;
    int N = (s == 0) ? 0 : n0 + n1;
    float fs = (float)s;
    const float* sb = obs + ((size_t)b * CHN + 4 + cg * 2) * NPX;

    for (int t = tid; t < N; t += 256) {
        float2 rv = (t < n0) ? r0[t] : r1[t - n0];
        int rem = __float_as_int(rv.x);
        float depth = rv.y;
        float px, py, pz;
        pix2pos(rem % WW, rem / WW, depth, ca, sa, foc, px, py, pz);
        float wy = 1.0f - fabsf(py - fs);
        if (wy <= 0.0f) continue;
        // cat-relevant z cells are [9,48]; record touches cells floor(pz)+{0,1}
        if (pz < 8.0f || pz >= 49.0f) continue;
        float fx = floorf(px);
        float fz = floorf(pz);
        bool xv0 = (fx > 0.0f && fx < 100.0f);
        bool xv1 = (fx + 1.0f > 0.0f && fx + 1.0f < 100.0f);
        if (!xv0 && !xv1) continue;
        float s0 = sb[rem];
        float s1 = sb[rem + NPX];
        #pragma unroll
        for (int i2 = 0; i2 < 2; i2++) {
            float cxp = fx + (float)i2;
            if (!(cxp > 0.0f && cxp < 100.0f)) continue;
            float wxy = wy * (1.0f - fabsf(px - cxp));
            int xi = (int)cxp;
            #pragma unroll
            for (int k = 0; k < 2; k++) {
                float czp = fz + (float)k;
                if (czp < 9.0f || czp > 48.0f) continue;
                float w3 = wxy * (1.0f - fabsf(pz - czp));
                if (w3 == 0.0f) continue;
                float* dst = &acc[(((int)czp - MINZ) * VRD + xi) * 2];
                atomicAdd(dst + 0, w3 * s0);
                atomicAdd(dst + 1, w3 * s1);
            }
        }
    }
    __syncthreads();

    // rint per voxel cell, then reduce over z. [z][x][c] layout: lane i reads
    // consecutive words (z*200 + i) -> conflict-free.
    for (int i = tid; i < VRD * 2; i += 256) {
        int x = i >> 1, c = i & 1;
        float ssum = 0.0f;
        #pragma unroll 4
        for (int z = 0; z < 40; z++)
            ssum += rintf(acc[(z * VRD + x) * 2 + c]);
        float v = fminf(fmaxf(ssum * 0.2f, 0.0f), 1.0f);
        maps[((size_t)(b * 18 + 2 + cg * 2 + c) * VRD + s) * VRD + x] = v;
    }
}

__device__ __forceinline__ void pose_params(const float* __restrict__ pose_obs,
                                            const float* __restrict__ poses_last,
                                            int b, float& ct, float& st,
                                            float& stx, float& sty) {
    const float DEG = 57.29577951308232f;
    float o  = poses_last[b*3+2] / DEG;
    float so = sinf(o), co = cosf(o);
    float yy = poses_last[b*3+1] + pose_obs[b*3+0]*so + pose_obs[b*3+1]*co;
    float xx = poses_last[b*3+0] + pose_obs[b*3+0]*co - pose_obs[b*3+1]*so;
    float tt = poses_last[b*3+2] + pose_obs[b*3+2]*DEG;
    tt = fmodf(tt - 180.0f, 360.0f) + 180.0f;
    tt = fmodf(tt + 180.0f, 360.0f) - 180.0f;
    stx = -((xx*100.0f/5.0f) - 240.0f) / 240.0f;
    sty = -((yy*100.0f/5.0f) - 240.0f) / 240.0f;
    float t = (90.0f - tt) * 0.017453292519943295f;
    ct = cosf(t); st = sinf(t);
}

__global__ __launch_bounds__(64) void pose_kernel(const float* __restrict__ pose_obs,
                                                  const float* __restrict__ poses_last,
                                                  float* __restrict__ out) {
    int b = threadIdx.x;
    if (b >= BS) return;
    const float DEG = 57.29577951308232f;
    float o  = poses_last[b*3+2] / DEG;
    float so = sinf(o), co = cosf(o);
    float yy = poses_last[b*3+1] + pose_obs[b*3+0]*so + pose_obs[b*3+1]*co;
    float xx = poses_last[b*3+0] + pose_obs[b*3+0]*co - pose_obs[b*3+1]*so;
    float tt = poses_last[b*3+2] + pose_obs[b*3+2]*DEG;
    tt = fmodf(tt - 180.0f, 360.0f) + 180.0f;
    tt = fmodf(tt + 180.0f, 360.0f) - 180.0f;
    out[OFF2 + b*3+0] = xx; out[OFF2 + b*3+1] = yy; out[OFF2 + b*3+2] = tt;
    out[OFF3 + b*3+0] = xx; out[OFF3 + b*3+1] = yy; out[OFF3 + b*3+2] = tt;
}

__global__ __launch_bounds__(256) void rotate_kernel(const float* __restrict__ maps,
                                                     const float* __restrict__ pose_obs,
                                                     const float* __restrict__ poses_last,
                                                     float* __restrict__ rot) {
    int idx = blockIdx.x * blockDim.x + threadIdx.x;
    if (idx >= BS * MM * MM) return;
    int b   = idx / (MM * MM);
    int rem = idx % (MM * MM);
    int y   = rem / MM;
    int x   = rem % MM;
    float ct, st, stx, sty;
    pose_params(pose_obs, poses_last, b, ct, st, stx, sty);
    float Xg = -1.0f + (float)x * (2.0f / 479.0f);
    float Yg = -1.0f + (float)y * (2.0f / 479.0f);
    float gx = ct * Xg - st * Yg;
    float gy = st * Xg + ct * Yg;
    float xf = (gx + 1.0f) * 0.5f * 479.0f;
    float yf = (gy + 1.0f) * 0.5f * 479.0f;
    float x0 = floorf(xf), y0 = floorf(yf);
    float fx = xf - x0, fy = yf - y0;
    float cw[4] = {(1.0f - fx) * (1.0f - fy), fx * (1.0f - fy),
                   (1.0f - fx) * fy,          fx * fy};
    float cx[4] = {x0, x0 + 1.0f, x0, x0 + 1.0f};
    float cy[4] = {y0, y0, y0 + 1.0f, y0 + 1.0f};
    float acc[18];
    #pragma unroll
    for (int m = 0; m < 18; m++) acc[m] = 0.0f;
    #pragma unroll
    for (int k = 0; k < 4; k++) {
        float fxk = cx[k], fyk = cy[k];
        if (!(fxk >= 0.0f && fxk <= 479.0f && fyk >= 0.0f && fyk <= 479.0f)) continue;
        int ix = (int)fxk, iy = (int)fyk;
        if (iy < 240 || iy >= 340 || ix < 190 || ix >= 290) continue;
        int mi = iy - 240, mj = ix - 190;
        float w = cw[k];
        const float* mp = maps + (size_t)b * 18 * VRD * VRD + mi * VRD + mj;
        #pragma unroll
        for (int m = 0; m < 18; m++) acc[m] += w * mp[(size_t)m * VRD * VRD];
    }
    size_t obase = ((size_t)b * CHN) * MM * MM + (size_t)y * MM + x;
    rot[obase + (size_t)0 * MM * MM] = acc[0];
    rot[obase + (size_t)1 * MM * MM] = acc[1];
    rot[obase + (size_t)2 * MM * MM] = 0.0f;
    rot[obase + (size_t)3 * MM * MM] = 0.0f;
    #pragma unroll
    for (int m = 2; m < 18; m++)
        rot[obase + (size_t)(m + 2) * MM * MM] = acc[m];
}

__global__ __launch_bounds__(256) void translate_kernel(const float* __restrict__ rot,
                                                        const float* __restrict__ pose_obs,
                                                        const float* __restrict__ poses_last,
                                                        float* __restrict__ tr) {
    int idx = blockIdx.x * blockDim.x + threadIdx.x;
    if (idx >= BS * MM * MM) return;
    int b   = idx / (MM * MM);
    int rem = idx % (MM * MM);
    int y   = rem / MM;
    int x   = rem % MM;
    float ct, st, stx, sty;
    pose_params(pose_obs, poses_last, b, ct, st, stx, sty);
    float Xg = -1.0f + (float)x * (2.0f / 479.0f);
    float Yg = -1.0f + (float)y * (2.0f / 479.0f);
    float xf = (Xg + stx + 1.0f) * 0.5f * 479.0f;
    float yf = (Yg + sty + 1.0f) * 0.5f * 479.0f;
    float x0 = floorf(xf), y0 = floorf(yf);
    float fx = xf - x0, fy = yf - y0;
    float cw[4] = {(1.0f - fx) * (1.0f - fy), fx * (1.0f - fy),
                   (1.0f - fx) * fy,          fx * fy};
    float cxs[4] = {x0, x0 + 1.0f, x0, x0 + 1.0f};
    float cys[4] = {y0, y0, y0 + 1.0f, y0 + 1.0f};
    bool vk[4]; int offk[4];
    #pragma unroll
    for (int k = 0; k < 4; k++) {
        vk[k] = (cxs[k] >= 0.0f && cxs[k] <= 479.0f && cys[k] >= 0.0f && cys[k] <= 479.0f);
        offk[k] = vk[k] ? ((int)cys[k] * MM + (int)cxs[k]) : 0;
    }
    #pragma unroll
    for (int c = 0; c < CHN; c++) {
        const float* rp = rot + ((size_t)b * CHN + c) * MM * MM;
        float v = 0.0f;
        #pragma unroll
        for (int k = 0; k < 4; k++)
            if (vk[k]) v += cw[k] * rp[offk[k]];
        tr[((size_t)b * CHN + c) * MM * MM + (size_t)y * MM + x] = v;
    }
}

__global__ __launch_bounds__(256) void max_kernel(const float* __restrict__ maps_last,
                                                  const float* __restrict__ tr,
                                                  float* __restrict__ mp) {
    int i = blockIdx.x * blockDim.x + threadIdx.x;
    int n4 = BS * CHN * MM * MM / 4;
    if (i >= n4) return;
    float4 a = ((const float4*)maps_last)[i];
    float4 t = ((const float4*)tr)[i];
    float4 r;
    r.x = fmaxf(a.x, t.x);
    r.y = fmaxf(a.y, t.y);
    r.z = fmaxf(a.z, t.z);
    r.w = fmaxf(a.w, t.w);
    ((float4*)mp)[i] = r;
}

extern "C" void kernel_launch(void* const* d_in, const int* in_sizes, int n_in,
                              void* d_out, int out_size, void* d_ws, size_t ws_size,
                              hipStream_t stream) {
    const float* obs         = (const float*)d_in[0];
    const float* pose_obs    = (const float*)d_in[1];
    const float* maps_last   = (const float*)d_in[2];
    const float* poses_last  = (const float*)d_in[3];
    const float* view_angles = (const float*)d_in[4];
    float* out = (float*)d_out;

    float*  maps = out + OFFM;
    float2* rec  = (float2*)(out + OFFR);
    int*    cnt  = (int*)(out + OFFC);

    hipMemsetAsync(cnt, 0, 400 * 16 * sizeof(int), stream);

    const float foc = (float)(320.0 / tan(39.5 * M_PI / 180.0));

    int npix = BS * NPX;
    bin_kernel<<<(npix + 255) / 256, 256, 0, stream>>>(obs, view_angles, cnt, rec, foc);

    dim3 sgrid(VRD, BS);
    slice_v0_kernel<<<sgrid, 256, 0, stream>>>(cnt, rec, view_angles, maps, out + OFF0, foc);
    // channel-split: 100 slices x 4 batches x 8 channel-groups, 1D for XCD swizzle
    slice_vc_kernel<<<dim3(VRD * BS * 8), 256, 0, stream>>>(obs, cnt, rec, view_angles,
                                                            maps, foc);

    pose_kernel<<<1, 64, 0, stream>>>(pose_obs, poses_last, out);

    int nmap = BS * MM * MM;
    rotate_kernel<<<(nmap + 255) / 256, 256, 0, stream>>>(maps, pose_obs, poses_last,
                                                          out + OFF1);
    translate_kernel<<<(nmap + 255) / 256, 256, 0, stream>>>(out + OFF1, pose_obs,
                                                             poses_last, out + OFF4);
    int n4 = BS * CHN * MM * MM / 4;
    max_kernel<<<(n4 + 255) / 256, 256, 0, stream>>>(maps_last, out + OFF4, out + OFF1);
}

// Round 2
// 1236.731 us; speedup vs baseline: 1.4353x; 1.0213x over previous
//
#include <hip/hip_runtime.h>
#include <math.h>

#define BS 4
#define HH 480
#define WW 640
#define NPX (HH * WW)          // 307200
#define NC 16
#define CHN 20
#define MM 480
#define VRD 100
#define ZHD 80
#define MINZ 9
#define MAXZ 49
#define CAP 8192                // records per (b, y-bucket)

// d_out float offsets
#define OFF0 0                  // fp_map_pred (40000)
#define OFF1 40000              // map_pred (18432000)  [scratch: geo records, then rotated mid]
#define OFF2 18472000           // current_poses (12)
#define OFF3 18472012           // current_poses (12)
#define OFF4 18472024           // translated (18432000)
#define OFFM 28840000           // maps scratch 4*18*100*100 = 720000 (inside OFF4, dead until translate)
#define OFFC 36113600           // counters: 400*16 ints (inside OFF4)
#define OFFS 36120000           // v0 staging: 2*4*100*100 floats = 80000 (inside OFF4)
#define GEO  40000              // geo records: 400*8192 float4 = 13107200 floats (inside OFF1)

__device__ __forceinline__ void pix2pos(int w, int h, float depth, float ca, float sa,
                                        float foc, float& px, float& py, float& pz) {
    float gx = (float)w;
    float gz = (float)(HH - 1 - h);
    float Xp = (gx - 319.5f) * depth / foc;
    float Zp = (gz - 239.5f) * depth / foc;
    float Yv = ca * depth - sa * Zp;
    float Zv = sa * depth + ca * Zp + 155.0f;
    float Xv = Xp + 250.0f;
    float xs = (Xv / 5.0f - 50.0f) / 100.0f * 2.0f;
    float ys = (Yv / 5.0f - 50.0f) / 100.0f * 2.0f;
    float zs = (Zv / 5.0f - 32.0f) / 80.0f * 2.0f;
    px = xs * 50.0f + 50.0f;
    py = ys * 50.0f + 50.0f;
    pz = zs * 40.0f + 40.0f;
}

// bin by y-bucket AND precompute geometry once: record = (px, py, pz, rem)
__global__ __launch_bounds__(256) void bin_kernel(const float* __restrict__ obs,
                                                  const float* __restrict__ va,
                                                  int* __restrict__ cnt,
                                                  float4* __restrict__ geo,
                                                  float foc) {
    int idx = blockIdx.x * blockDim.x + threadIdx.x;
    if (idx >= BS * NPX) return;
    int b   = idx / NPX;
    int rem = idx % NPX;
    float depth = obs[((size_t)b * CHN + 3) * NPX + rem];
    int h = rem / WW, w = rem % WW;
    float a  = va[b] * 0.017453292519943295f;
    float ca = cosf(a), sa = sinf(a);
    float px, py, pz;
    pix2pos(w, h, depth, ca, sa, foc, px, py, pz);
    int f = (int)floorf(py);
    if (f < 0 || f > 99) return;
    int slot = atomicAdd(cnt + (b * VRD + f) * 16, 1);
    if (slot < CAP) {
        float4 r;
        r.x = px; r.y = py; r.z = pz; r.w = __int_as_float(rem);
        geo[(size_t)(b * VRD + f) * CAP + slot] = r;
    }
}

// unified slice kernel: grid = 100 slices x 4 batches x 18 "channels".
// c in [0,16): semantic channel c, z-cells [9,49), output -> maps[2+c]
// c = 16:     occupancy, z-cells [1,40)   -> partial sums into staging
// c = 17:     occupancy, z-cells [40,80)  -> partial sums into staging
// 16 KB LDS accumulator; 4-way record batching for memory-level parallelism.
__global__ __launch_bounds__(256, 6) void slice_kernel(const float* __restrict__ obs,
                                                       const int* __restrict__ cnt,
                                                       const float4* __restrict__ geo,
                                                       float* __restrict__ maps,
                                                       float* __restrict__ stage) {
    __shared__ float acc[40 * VRD];   // 16 KB
    int bid  = blockIdx.x;                       // 0..7199
    int wgid = (bid & 7) * 900 + (bid >> 3);     // bijective XCD swizzle (7200 % 8 == 0)
    int s  = wgid % VRD;
    int p  = wgid / VRD;                         // 0..71
    int b  = p & 3;
    int c  = p >> 2;                             // 0..17
    int tid = threadIdx.x;
    for (int i = tid; i < 40 * VRD; i += 256) acc[i] = 0.0f;
    __syncthreads();

    bool isocc = (c >= 16);
    float clo   = isocc ? ((c == 16) ? 1.0f : 40.0f) : 9.0f;   // valid z-cell window [clo, chi)
    float chi   = isocc ? ((c == 16) ? 40.0f : 80.0f) : 49.0f;
    int   zbase = isocc ? ((c == 16) ? 0 : 40) : 9;
    const float* sb = isocc ? (const float*)0 : obs + ((size_t)b * CHN + 4 + c) * NPX;

    int sm1 = (s > 0) ? s - 1 : 0;
    int n0 = (s > 0) ? min(cnt[(b * VRD + sm1) * 16], CAP) : 0;
    int n1 = min(cnt[(b * VRD + s) * 16], CAP);
    const float4* g0 = geo + (size_t)(b * VRD + sm1) * CAP;
    const float4* g1 = geo + (size_t)(b * VRD + s) * CAP;
    int N = (s == 0) ? 0 : n0 + n1;
    float fs = (float)s;

    for (int base = tid * 4; base < N; base += 1024) {
        float4 g[4];
        #pragma unroll
        for (int j = 0; j < 4; j++) {
            int t = base + j;
            g[j] = (t < N) ? ((t < n0) ? g0[t] : g1[t - n0])
                           : make_float4(0.0f, -10.0f, 0.0f, 0.0f);
        }
        bool act[4];
        #pragma unroll
        for (int j = 0; j < 4; j++) {
            float wy = 1.0f - fabsf(g[j].y - fs);
            bool ok = (wy > 0.0f);
            ok = ok && (g[j].z > clo - 1.0f) && (g[j].z < chi);
            float fx = floorf(g[j].x);
            ok = ok && (fx + 1.0f > 0.0f) && (fx < 100.0f);
            act[j] = ok;
        }
        float sv[4];
        #pragma unroll
        for (int j = 0; j < 4; j++)
            sv[j] = (!isocc && act[j]) ? sb[__float_as_int(g[j].w)] : 1.0f;
        #pragma unroll
        for (int j = 0; j < 4; j++) {
            if (!act[j]) continue;
            float px = g[j].x, pz = g[j].z;
            float wy = 1.0f - fabsf(g[j].y - fs);
            float fx = floorf(px), fz = floorf(pz);
            #pragma unroll
            for (int i2 = 0; i2 < 2; i2++) {
                float cxp = fx + (float)i2;
                if (!(cxp > 0.0f && cxp < 100.0f)) continue;
                float wxy = wy * (1.0f - fabsf(px - cxp));
                int xi = (int)cxp;
                #pragma unroll
                for (int k = 0; k < 2; k++) {
                    float czp = fz + (float)k;
                    if (czp < clo || czp >= chi) continue;
                    float w3 = wxy * (1.0f - fabsf(pz - czp));
                    if (w3 == 0.0f) continue;
                    atomicAdd(&acc[((int)czp - zbase) * VRD + xi], w3 * sv[j]);
                }
            }
        }
    }
    __syncthreads();

    if (!isocc) {
        for (int x = tid; x < VRD; x += 256) {
            float ssum = 0.0f;
            #pragma unroll 8
            for (int z = 0; z < 40; z++) ssum += rintf(acc[z * VRD + x]);
            maps[((size_t)(b * 18 + 2 + c) * VRD + s) * VRD + x] =
                fminf(fmaxf(ssum * 0.2f, 0.0f), 1.0f);
        }
    } else {
        int cell0 = (c == 16) ? 0 : 40;
        for (int x = tid; x < VRD; x += 256) {
            float s_all = 0.0f, s_agg = 0.0f;
            #pragma unroll 8
            for (int z = 0; z < 40; z++) {
                float r = rintf(acc[z * VRD + x]);
                s_all += r;
                int cell = cell0 + z;
                if (cell >= MINZ && cell < MAXZ) s_agg += r;
            }
            int o = (b * VRD + s) * VRD + x;
            atomicAdd(stage + o, s_all);
            atomicAdd(stage + 40000 + o, s_agg);
        }
    }
}

// combine occupancy partial sums -> maps ch0/ch1 + fp_map_pred output
__global__ __launch_bounds__(256) void fixup_kernel(const float* __restrict__ stage,
                                                    float* __restrict__ maps,
                                                    float* __restrict__ out0) {
    int idx = blockIdx.x * blockDim.x + threadIdx.x;
    if (idx >= BS * VRD * VRD) return;
    int b = idx / (VRD * VRD);
    int r = idx % (VRD * VRD);
    float all = stage[idx];
    float agg = stage[40000 + idx];
    float fm = fminf(fmaxf(agg, 0.0f), 1.0f);
    float fe = fminf(fmaxf(all, 0.0f), 1.0f);
    maps[(size_t)(b * 18 + 0) * 10000 + r] = fm;
    maps[(size_t)(b * 18 + 1) * 10000 + r] = fe;
    out0[idx] = fm;
}

__device__ __forceinline__ void pose_params(const float* __restrict__ pose_obs,
                                            const float* __restrict__ poses_last,
                                            int b, float& ct, float& st,
                                            float& stx, float& sty) {
    const float DEG = 57.29577951308232f;
    float o  = poses_last[b*3+2] / DEG;
    float so = sinf(o), co = cosf(o);
    float yy = poses_last[b*3+1] + pose_obs[b*3+0]*so + pose_obs[b*3+1]*co;
    float xx = poses_last[b*3+0] + pose_obs[b*3+0]*co - pose_obs[b*3+1]*so;
    float tt = poses_last[b*3+2] + pose_obs[b*3+2]*DEG;
    tt = fmodf(tt - 180.0f, 360.0f) + 180.0f;
    tt = fmodf(tt + 180.0f, 360.0f) - 180.0f;
    stx = -((xx*100.0f/5.0f) - 240.0f) / 240.0f;
    sty = -((yy*100.0f/5.0f) - 240.0f) / 240.0f;
    float t = (90.0f - tt) * 0.017453292519943295f;
    ct = cosf(t); st = sinf(t);
}

__global__ __launch_bounds__(64) void pose_kernel(const float* __restrict__ pose_obs,
                                                  const float* __restrict__ poses_last,
                                                  float* __restrict__ out) {
    int b = threadIdx.x;
    if (b >= BS) return;
    const float DEG = 57.29577951308232f;
    float o  = poses_last[b*3+2] / DEG;
    float so = sinf(o), co = cosf(o);
    float yy = poses_last[b*3+1] + pose_obs[b*3+0]*so + pose_obs[b*3+1]*co;
    float xx = poses_last[b*3+0] + pose_obs[b*3+0]*co - pose_obs[b*3+1]*so;
    float tt = poses_last[b*3+2] + pose_obs[b*3+2]*DEG;
    tt = fmodf(tt - 180.0f, 360.0f) + 180.0f;
    tt = fmodf(tt + 180.0f, 360.0f) - 180.0f;
    out[OFF2 + b*3+0] = xx; out[OFF2 + b*3+1] = yy; out[OFF2 + b*3+2] = tt;
    out[OFF3 + b*3+0] = xx; out[OFF3 + b*3+1] = yy; out[OFF3 + b*3+2] = tt;
}

__global__ __launch_bounds__(256) void rotate_kernel(const float* __restrict__ maps,
                                                     const float* __restrict__ pose_obs,
                                                     const float* __restrict__ poses_last,
                                                     float* __restrict__ rot) {
    int idx = blockIdx.x * blockDim.x + threadIdx.x;
    if (idx >= BS * MM * MM) return;
    int b   = idx / (MM * MM);
    int rem = idx % (MM * MM);
    int y   = rem / MM;
    int x   = rem % MM;
    float ct, st, stx, sty;
    pose_params(pose_obs, poses_last, b, ct, st, stx, sty);
    float Xg = -1.0f + (float)x * (2.0f / 479.0f);
    float Yg = -1.0f + (float)y * (2.0f / 479.0f);
    float gx = ct * Xg - st * Yg;
    float gy = st * Xg + ct * Yg;
    float xf = (gx + 1.0f) * 0.5f * 479.0f;
    float yf = (gy + 1.0f) * 0.5f * 479.0f;
    float x0 = floorf(xf), y0 = floorf(yf);
    float fx = xf - x0, fy = yf - y0;
    float cw[4] = {(1.0f - fx) * (1.0f - fy), fx * (1.0f - fy),
                   (1.0f - fx) * fy,          fx * fy};
    float cx[4] = {x0, x0 + 1.0f, x0, x0 + 1.0f};
    float cy[4] = {y0, y0, y0 + 1.0f, y0 + 1.0f};
    float acc[18];
    #pragma unroll
    for (int m = 0; m < 18; m++) acc[m] = 0.0f;
    #pragma unroll
    for (int k = 0; k < 4; k++) {
        float fxk = cx[k], fyk = cy[k];
        if (!(fxk >= 0.0f && fxk <= 479.0f && fyk >= 0.0f && fyk <= 479.0f)) continue;
        int ix = (int)fxk, iy = (int)fyk;
        if (iy < 240 || iy >= 340 || ix < 190 || ix >= 290) continue;
        int mi = iy - 240, mj = ix - 190;
        float w = cw[k];
        const float* mp = maps + (size_t)b * 18 * VRD * VRD + mi * VRD + mj;
        #pragma unroll
        for (int m = 0; m < 18; m++) acc[m] += w * mp[(size_t)m * VRD * VRD];
    }
    size_t obase = ((size_t)b * CHN) * MM * MM + (size_t)y * MM + x;
    rot[obase + (size_t)0 * MM * MM] = acc[0];
    rot[obase + (size_t)1 * MM * MM] = acc[1];
    rot[obase + (size_t)2 * MM * MM] = 0.0f;
    rot[obase + (size_t)3 * MM * MM] = 0.0f;
    #pragma unroll
    for (int m = 2; m < 18; m++)
        rot[obase + (size_t)(m + 2) * MM * MM] = acc[m];
}

__global__ __launch_bounds__(256) void translate_kernel(const float* __restrict__ rot,
                                                        const float* __restrict__ pose_obs,
                                                        const float* __restrict__ poses_last,
                                                        float* __restrict__ tr) {
    int idx = blockIdx.x * blockDim.x + threadIdx.x;
    if (idx >= BS * MM * MM) return;
    int b   = idx / (MM * MM);
    int rem = idx % (MM * MM);
    int y   = rem / MM;
    int x   = rem % MM;
    float ct, st, stx, sty;
    pose_params(pose_obs, poses_last, b, ct, st, stx, sty);
    float Xg = -1.0f + (float)x * (2.0f / 479.0f);
    float Yg = -1.0f + (float)y * (2.0f / 479.0f);
    float xf = (Xg + stx + 1.0f) * 0.5f * 479.0f;
    float yf = (Yg + sty + 1.0f) * 0.5f * 479.0f;
    float x0 = floorf(xf), y0 = floorf(yf);
    float fx = xf - x0, fy = yf - y0;
    float cw[4] = {(1.0f - fx) * (1.0f - fy), fx * (1.0f - fy),
                   (1.0f - fx) * fy,          fx * fy};
    float cxs[4] = {x0, x0 + 1.0f, x0, x0 + 1.0f};
    float cys[4] = {y0, y0, y0 + 1.0f, y0 + 1.0f};
    bool vk[4]; int offk[4];
    #pragma unroll
    for (int k = 0; k < 4; k++) {
        vk[k] = (cxs[k] >= 0.0f && cxs[k] <= 479.0f && cys[k] >= 0.0f && cys[k] <= 479.0f);
        offk[k] = vk[k] ? ((int)cys[k] * MM + (int)cxs[k]) : 0;
    }
    #pragma unroll
    for (int c = 0; c < CHN; c++) {
        const float* rp = rot + ((size_t)b * CHN + c) * MM * MM;
        float v = 0.0f;
        #pragma unroll
        for (int k = 0; k < 4; k++)
            if (vk[k]) v += cw[k] * rp[offk[k]];
        tr[((size_t)b * CHN + c) * MM * MM + (size_t)y * MM + x] = v;
    }
}

__global__ __launch_bounds__(256) void max_kernel(const float* __restrict__ maps_last,
                                                  const float* __restrict__ tr,
                                                  float* __restrict__ mp) {
    int i = blockIdx.x * blockDim.x + threadIdx.x;
    int n4 = BS * CHN * MM * MM / 4;
    if (i >= n4) return;
    float4 a = ((const float4*)maps_last)[i];
    float4 t = ((const float4*)tr)[i];
    float4 r;
    r.x = fmaxf(a.x, t.x);
    r.y = fmaxf(a.y, t.y);
    r.z = fmaxf(a.z, t.z);
    r.w = fmaxf(a.w, t.w);
    ((float4*)mp)[i] = r;
}

extern "C" void kernel_launch(void* const* d_in, const int* in_sizes, int n_in,
                              void* d_out, int out_size, void* d_ws, size_t ws_size,
                              hipStream_t stream) {
    const float* obs         = (const float*)d_in[0];
    const float* pose_obs    = (const float*)d_in[1];
    const float* maps_last   = (const float*)d_in[2];
    const float* poses_last  = (const float*)d_in[3];
    const float* view_angles = (const float*)d_in[4];
    float* out = (float*)d_out;

    float*  maps  = out + OFFM;
    float4* geo   = (float4*)(out + GEO);
    int*    cnt   = (int*)(out + OFFC);
    float*  stage = out + OFFS;

    // zero counters + occupancy staging (contiguous)
    hipMemsetAsync(cnt, 0, (6400 + 80000) * sizeof(float), stream);

    const float foc = (float)(320.0 / tan(39.5 * M_PI / 180.0));

    int npix = BS * NPX;
    bin_kernel<<<(npix + 255) / 256, 256, 0, stream>>>(obs, view_angles, cnt, geo, foc);

    // 100 slices x 4 batches x 18 channels (16 sem + 2 occupancy z-halves)
    slice_kernel<<<dim3(VRD * BS * 18), 256, 0, stream>>>(obs, cnt, geo, maps, stage);

    fixup_kernel<<<(BS * VRD * VRD + 255) / 256, 256, 0, stream>>>(stage, maps, out + OFF0);

    pose_kernel<<<1, 64, 0, stream>>>(pose_obs, poses_last, out);

    int nmap = BS * MM * MM;
    rotate_kernel<<<(nmap + 255) / 256, 256, 0, stream>>>(maps, pose_obs, poses_last,
                                                          out + OFF1);
    translate_kernel<<<(nmap + 255) / 256, 256, 0, stream>>>(out + OFF1, pose_obs,
                                                             poses_last, out + OFF4);
    int n4 = BS * CHN * MM * MM / 4;
    max_kernel<<<(n4 + 255) / 256, 256, 0, stream>>>(maps_last, out + OFF4, out + OFF1);
}